// Round 1
// 404.470 us; speedup vs baseline: 1.0138x; 1.0138x over previous
//
#include <hip/hip_runtime.h>
#include <stdint.h>

#define BATCH 65536
#define FDIM 512
#define HDIM 256
#define NC 10
#define NREP 16

typedef short short8 __attribute__((ext_vector_type(8)));
typedef float f32x4 __attribute__((ext_vector_type(4)));

// ---- workspace layout (bytes) ----
// Fragment-tiled layout: tile (I=row/16, C=k/32) is 1KB at (I*nC + C)*1024;
// slot l = (row&15) | (((k>>3)&3)<<4) holds 8 bf16 (k = (l>>4)*8 .. +7).
#define OFF_FC0T   ((size_t)0)                          // 32 J x 16 C tiles
#define OFF_FC1T   (OFF_FC0T + (size_t)512*512*2)
#define OFF_WT     (OFF_FC1T + (size_t)512*512*2)       // 16 J x 16 C tiles
#define OFF_XT     (OFF_WT   + (size_t)256*512*2)       // 4096 I x 16 C (64MB)
#define OFF_X4T    (OFF_XT   + (size_t)BATCH*512*2)     // 4096 I x 16 C (64MB)
#define OFF_ACC    (OFF_X4T  + (size_t)BATCH*512*2)
#define SCAL_SUMSQ 0
#define SCAL_CE    16
#define SCAL_ACC   32
#define SCAL_L1    48
#define SCAL_N     128
#define CNT_OFF    SCAL_N                 // NREP*16 floats
#define GSUM_OFF   (SCAL_N + NREP*16)     // NREP*5120 floats
#define ACC_FLOATS (GSUM_OFF + NREP*5120) // 82304 floats
#define OFF_W1T    (OFF_ACC + (size_t)ACC_FLOATS*4)     // 8 C-tiles x 1KB (w1 bf16, padded to 16 classes)

#define GLL(g,l) __builtin_amdgcn_global_load_lds((const __attribute__((address_space(1))) void*)(g), (__attribute__((address_space(3))) void*)(l), 16, 0, 0)

__device__ __forceinline__ unsigned short f2b(float f){
  unsigned u = __float_as_uint(f);
  u += 0x7FFFu + ((u >> 16) & 1u);
  return (unsigned short)(u >> 16);
}
__device__ __forceinline__ float b2f(unsigned short h){
  return __uint_as_float(((unsigned)h) << 16);
}
__device__ __forceinline__ unsigned pk2b(float f0, float f1){
  unsigned u0 = __float_as_uint(f0) + 0x8000u;
  unsigned u1 = __float_as_uint(f1) + 0x8000u;
  return __builtin_amdgcn_perm(u1, u0, 0x07060302u);
}

// ---- K0: setup — xcast (blocks 0..1023), weight prep (1024..1359), zero (1360..1440)
__global__ __launch_bounds__(256) void k_setup(
    const float* __restrict__ x,   const float* __restrict__ fc0,
    const float* __restrict__ fc1, const float* __restrict__ w,
    const float* __restrict__ w1,
    unsigned short* __restrict__ xT,   unsigned short* __restrict__ fc0T,
    unsigned short* __restrict__ fc1T, unsigned short* __restrict__ wT,
    unsigned short* __restrict__ w1T,  float* __restrict__ accb)
{
  int blk = blockIdx.x, t = threadIdx.x;
  if (blk < 1024){
    int I = blk*4 + (t >> 6);
    int l = t & 63;
    int row = I*16 + (l & 15), q = l >> 4;
    const float* src = x + (size_t)row*FDIM + q*8;
    #pragma unroll
    for (int C = 0; C < 16; ++C){
      float4 v0 = *(const float4*)(src + C*32);
      float4 v1 = *(const float4*)(src + C*32 + 4);
      unsigned o[4];
      o[0] = pk2b(v0.x, v0.y); o[1] = pk2b(v0.z, v0.w);
      o[2] = pk2b(v1.x, v1.y); o[3] = pk2b(v1.z, v1.w);
      *(short8*)&xT[(((size_t)I*16 + C) << 9) + l*8] = *(short8*)o;
    }
    return;
  }
  if (blk < 1360){
    int i = (blk - 1024)*256 + t;
    float l1v = 0.f;
    if (i < 32768){                       // fc0 [k][512] -> tiled
      int n4 = i&15, m = (i>>4)&3, C = (i>>6)&15, J = i>>10;
      int n = J*16+n4, k8 = C*4+m;
      unsigned short o[8];
      #pragma unroll
      for (int j=0;j<8;++j){ float v = fc0[(size_t)(k8*8+j)*512 + n]; o[j]=f2b(v); l1v += fabsf(v); }
      *(short8*)&fc0T[(size_t)(J*16+C)*512 + (i&63)*8] = *(short8*)o;
    } else if (i < 65536){                // fc1
      int j0 = i - 32768;
      int n4 = j0&15, m = (j0>>4)&3, C = (j0>>6)&15, J = j0>>10;
      int n = J*16+n4, k8 = C*4+m;
      unsigned short o[8];
      #pragma unroll
      for (int j=0;j<8;++j){ float v = fc1[(size_t)(k8*8+j)*512 + n]; o[j]=f2b(v); l1v += fabsf(v); }
      *(short8*)&fc1T[(size_t)(J*16+C)*512 + (j0&63)*8] = *(short8*)o;
    } else if (i < 81920){                // w [k][256]
      int j0 = i - 65536;
      int n4 = j0&15, m = (j0>>4)&3, C = (j0>>6)&15, J = j0>>10;
      int n = J*16+n4, k8 = C*4+m;
      unsigned short o[8];
      #pragma unroll
      for (int j=0;j<8;++j){ float v = w[(size_t)(k8*8+j)*256 + n]; o[j]=f2b(v); l1v += fabsf(v); }
      *(short8*)&wT[(size_t)(J*16+C)*512 + (j0&63)*8] = *(short8*)o;
    } else if (i < 86016){                // w1 -> B-fragment tiles (16 classes padded), + L1
      int j0 = i - 81920;                 // 0..4095, one bf16 each
      int C = j0 >> 9, l = (j0 >> 3) & 63, e = j0 & 7;
      int n = l & 15, k = C*32 + (l>>4)*8 + e;
      float v = (n < NC) ? w1[k*NC + n] : 0.f;
      w1T[C*512 + l*8 + e] = f2b(v);
      if (n < NC) l1v = fabsf(v);
    }
    for (int off = 32; off; off >>= 1) l1v += __shfl_down(l1v, off);
    if ((t & 63) == 0 && l1v != 0.f)
      atomicAdd(&accb[SCAL_L1 + (blk & (NREP-1))], l1v);
    return;
  }
  {
    int base = (blk - 1360)*1024;
    #pragma unroll
    for (int j=0;j<4;++j){
      int idx = base + j*256 + t;
      if (idx < ACC_FLOATS) accb[idx] = 0.f;
    }
  }
}

// ---------------------------------------------------------------------------
// K1: dual GEMM, 8-phase counted-vmcnt pipeline (T3+T4+T5 port of the 256^2
// template). Block = 256 rows x 128 cols x {fc0,fc1}; 8 waves (2r x 4c);
// BK=64, double-buffered 128KB LDS; per phase: 16 MFMA + 1 half-tile stage
// (2 GLL/wave); vmcnt(4) once per K-tile, NEVER 0 in steady state.
// Phase quadrants per K-tile: (Ah0,B0)(Ah1,B0)(Ah1,B1)(Ah0,B1); the region a
// phase stages into died >=1 phase earlier (B0 dead after p0-reads, Ah1 after
// p1-reads); cross-buffer stages (p0,p1) are trivially safe.
// ---------------------------------------------------------------------------

#define BARRIER() __builtin_amdgcn_s_barrier()
#define LGKM0() do{ asm volatile("s_waitcnt lgkmcnt(0)" ::: "memory"); \
                    __builtin_amdgcn_sched_barrier(0); }while(0)

#define READA(A, AB, H) do{                                                   \
  _Pragma("unroll") for (int c_=0;c_<2;++c_)                                  \
  _Pragma("unroll") for (int m_=0;m_<4;++m_)                                  \
    A[c_][m_] = *(const short8*)((AB) + (((wr*8 + (H)*4 + m_)*2 + c_)<<10) + lane*16); \
}while(0)

#define READB(B, BB, MAT) do{                                                 \
  _Pragma("unroll") for (int c_=0;c_<2;++c_)                                  \
  _Pragma("unroll") for (int n_=0;n_<2;++n_)                                  \
    B[c_][n_] = *(const short8*)((BB) + (MAT)*16384 + (((wc*2+n_)*2 + c_)<<10) + lane*16); \
}while(0)

#define MM(ACC, MB, A, B) do{                                                 \
  __builtin_amdgcn_s_setprio(1);                                              \
  _Pragma("unroll") for (int c_=0;c_<2;++c_)                                  \
  _Pragma("unroll") for (int n_=0;n_<2;++n_)                                  \
  _Pragma("unroll") for (int m_=0;m_<4;++m_)                                  \
    ACC[(MB)+m_][n_] = __builtin_amdgcn_mfma_f32_16x16x32_bf16(A[c_][m_], B[c_][n_], ACC[(MB)+m_][n_], 0,0,0); \
  __builtin_amdgcn_s_setprio(0);                                              \
}while(0)

// stage one 16KB A-half (16 tiles): wave wv does tiles {wv, 8+wv}
#define STAGEA(KT2, H) do{                                                    \
  char* d_ = ldsd + (((KT2)&1) ? 65536 : 0);                                  \
  _Pragma("unroll") for (int r_=0;r_<2;++r_){                                 \
    int idx_ = r_*8 + wv, q_ = idx_>>1, C_ = idx_&1;                          \
    int Il_ = (q_&3) + ((q_>>2)<<3) + (H)*4;                                  \
    GLL(xb + (((size_t)((rowblk*16 + Il_)*16 + (KT2)*2 + C_)) << 10) + lane*16, \
        d_ + ((Il_*2 + C_) << 10) + lane*16);                                 \
  } }while(0)

// stage one 16KB B-half (one matrix's 8 J-tiles x 2 C)
#define STAGEB(KT2, MAT) do{                                                  \
  char* d_ = ldsd + (((KT2)&1) ? 65536 : 0) + 32768 + (MAT)*16384;            \
  const char* s_ = (MAT) ? b1b : b0b;                                         \
  _Pragma("unroll") for (int r_=0;r_<2;++r_){                                 \
    int idx_ = r_*8 + wv, J_ = idx_>>1, C_ = idx_&1;                          \
    GLL(s_ + (((size_t)((colblk*8 + J_)*16 + (KT2)*2 + C_)) << 10) + lane*16, \
        d_ + ((J_*2 + C_) << 10) + lane*16);                                  \
  } }while(0)

__global__ __launch_bounds__(512, 2) void k_gemm12(
    const unsigned short* __restrict__ xT,
    const unsigned short* __restrict__ fc0T,
    const unsigned short* __restrict__ fc1T,
    unsigned short* __restrict__ x4T,
    float* __restrict__ scal)
{
  extern __shared__ __align__(16) char ldsd[];   // 131072 dynamic

  int blk = blockIdx.x;
  int wg = (blk & 7)*128 + (blk >> 3);           // bijective XCD chunking (1024%8==0)
  int rowblk = wg >> 2;                          // 0..255 (256 rows each)
  int colblk = wg & 3;                           // 0..3   (128 cols each)

  int t = threadIdx.x;
  int wv = t >> 6, lane = t & 63, ln = lane & 15, quad = lane >> 4;
  int wr = wv >> 2, wc = wv & 3;                 // 2 x 4 wave grid

  const char* xb  = (const char*)xT;
  const char* b0b = (const char*)fc0T;
  const char* b1b = (const char*)fc1T;

  const f32x4 zv = {0.f,0.f,0.f,0.f};
  f32x4 acc1[8][2], acc2[8][2];
  #pragma unroll
  for (int m=0;m<8;++m){ acc1[m][0]=zv; acc1[m][1]=zv; acc2[m][0]=zv; acc2[m][1]=zv; }

  // ---- prologue: Kt0 fully + prime Bfc0(1), Ah1(1); leave 4 GLL in flight
  STAGEA(0,0); STAGEA(0,1); STAGEB(0,0); STAGEB(0,1);
  STAGEB(1,0); STAGEA(1,1);
  asm volatile("s_waitcnt vmcnt(4)" ::: "memory");
  __builtin_amdgcn_sched_barrier(0);
  BARRIER();

  short8 a0[2][4], a1[2][4], bb[2][2];

  for (int kt = 0; kt < 8; ++kt){
    char* Ab = ldsd + ((kt&1) ? 65536 : 0);
    char* Bb = Ab + 32768;

    // p0: read Ah0 + Bfc0; stage Ah0(kt+1) -> other buf
    READA(a0, Ab, 0);
    READB(bb, Bb, 0);
    if (kt < 7) STAGEA(kt+1, 0);
    BARRIER(); LGKM0();
    MM(acc1, 0, a0, bb);
    BARRIER();

    // p1: read Ah1 (reuse Bfc0 regs); stage Bfc1(kt+1) -> other buf
    READA(a1, Ab, 1);
    if (kt < 7) STAGEB(kt+1, 1);
    BARRIER(); LGKM0();
    MM(acc1, 4, a1, bb);
    BARRIER();

    // p2: read Bfc1 (reuse Ah1 regs); stage Bfc0(kt+2) into NOW-DEAD region
    READB(bb, Bb, 1);
    if (kt < 6) STAGEB(kt+2, 0);
    BARRIER(); LGKM0();
    MM(acc2, 4, a1, bb);
    BARRIER();

    // p3: re-read Ah0 (reuse Bfc1 regs); stage Ah1(kt+2) into NOW-DEAD region
    READA(a0, Ab, 0);
    if (kt < 6) STAGEA(kt+2, 1);
    BARRIER(); LGKM0();
    MM(acc2, 0, a0, bb);
    // end-of-K-tile wait: retires exactly Kt kt+1's 4 halves, keeps 2 in flight
    if (kt < 6)       { asm volatile("s_waitcnt vmcnt(4)" ::: "memory"); }
    else if (kt == 6) { asm volatile("s_waitcnt vmcnt(0)" ::: "memory"); }
    __builtin_amdgcn_sched_barrier(0);
    BARRIER();
  }

  // ---- epilogue: residual x into buf0 region, x4 bf16 into buf1 region
  {
    int Cres = colblk*4 + wc;
    #pragma unroll
    for (int i = 0; i < 8; ++i){
      GLL(xb + (((size_t)((rowblk*16 + wr*8 + i)*16 + Cres)) << 10) + lane*16,
          ldsd + ((wv*8 + i) << 10) + lane*16);
    }
    asm volatile("s_waitcnt vmcnt(0)" ::: "memory");
  }
  __syncthreads();

  unsigned short* resU = (unsigned short*)ldsd;
  unsigned short* x4U  = (unsigned short*)(ldsd + 65536);
  float sumsq = 0.f;
  #pragma unroll
  for (int m = 0; m < 8; ++m){
    #pragma unroll
    for (int n = 0; n < 2; ++n){
      #pragma unroll
      for (int r = 0; r < 4; ++r){
        int slot = (quad*4 + r) | ((n*2 + (ln>>3)) << 4);
        int idx = ((wv*8 + m) << 9) + slot*8 + (ln & 7);
        float xv  = b2f(resU[idx]);
        float x1v = acc1[m][n][r];
        float x2v = fmaxf(acc2[m][n][r], 0.f);
        float gate = 1.f + 1.f/(1.f + __expf(-x1v));
        float x4v = fmaf(gate, x2v, xv);
        unsigned short ub = f2b(x4v);
        float fq = b2f(ub);
        sumsq = fmaf(fq, fq, sumsq);
        x4U[idx] = ub;
      }
    }
  }
  for (int off = 32; off; off >>= 1) sumsq += __shfl_down(sumsq, off);
  __syncthreads();                         // all res reads + x4 writes done
  float* red = (float*)ldsd;               // overwrite dead res region
  if (lane == 0) red[wv] = sumsq;
  __syncthreads();
  if (t == 0){
    float s = 0.f;
    #pragma unroll
    for (int i=0;i<8;++i) s += red[i];
    atomicAdd(&scal[SCAL_SUMSQ + (blk & (NREP-1))], s);
  }
  // copy x4 LDS -> global (16B stores)
  #pragma unroll
  for (int r = 0; r < 2; ++r){
    int o = r*512 + t;
    int tile = o >> 6, off16 = o & 63;
    int wvp = tile >> 3, i = tile & 7;
    size_t Ig = (size_t)rowblk*16 + (wvp>>2)*8 + i;
    int Cg = colblk*4 + (wvp & 3);
    *(short8*)&x4T[((Ig*16 + Cg) << 9) + off16*8] =
      *(const short8*)&x4U[(tile << 9) + off16*8];
  }
}

// class sums from tiled x4: one wave per (C-phase, 64 I-tiles) — R3-proven
__global__ __launch_bounds__(256) void k_csum(const unsigned short* __restrict__ x4T,
                                              const int* __restrict__ y,
                                              float* __restrict__ gsum){
  int w = blockIdx.x*4 + (threadIdx.x >> 6);   // 1024 waves
  int l = threadIdx.x & 63;
  int C = w & 15, Ig = w >> 4;                 // Ig 0..63
  int rl = l & 15, q = l >> 4;
  float a[NC][8];
  #pragma unroll
  for (int c=0;c<NC;++c)
    #pragma unroll
    for (int e=0;e<8;++e) a[c][e]=0.f;
  for (int ii = 0; ii < 64; ++ii){
    int I = Ig*64 + ii;
    int yv = y[I*16 + rl];
    short8 v = *(const short8*)&x4T[(((size_t)I*16 + C) << 9) + l*8];
    float f[8];
    #pragma unroll
    for (int e=0;e<8;++e) f[e] = b2f((unsigned short)v[e]);
    #pragma unroll
    for (int c=0;c<NC;++c){
      bool m = (yv == c);
      #pragma unroll
      for (int e=0;e<8;++e) a[c][e] += m ? f[e] : 0.f;
    }
  }
  #pragma unroll
  for (int off = 1; off < 16; off <<= 1)
    #pragma unroll
    for (int c=0;c<NC;++c)
      #pragma unroll
      for (int e=0;e<8;++e) a[c][e] += __shfl_xor(a[c][e], off);
  if (rl == 0){
    int rep = Ig & (NREP-1);
    int kb = C*32 + q*8;
    #pragma unroll
    for (int c=0;c<NC;++c)
      #pragma unroll
      for (int e=0;e<8;++e)
        atomicAdd(&gsum[(size_t)rep*5120 + c*512 + kb + e], a[c][e]);
  }
}

// counts of each class
__global__ __launch_bounds__(256) void k_cnt(const int* __restrict__ y,
                                             float* __restrict__ gcnt){
  __shared__ float cntS[NC];
  int t = threadIdx.x;
  if (t < NC) cntS[t] = 0.f;
  __syncthreads();
  int base = blockIdx.x*2048;
  for (int i = t; i < 2048; i += 256) atomicAdd(&cntS[y[base+i]], 1.f);
  __syncthreads();
  if (t < NC) atomicAdd(&gcnt[(blockIdx.x & (NREP-1))*16 + t], cntS[t]);
}

// K2: h = relu(x4 @ w) (LDS only); logits = h @ w1 via MFMA; CE/argmax/acc.
__global__ __launch_bounds__(512) void k_gemm3_head(
    const unsigned short* __restrict__ x4T,
    const unsigned short* __restrict__ wT,
    const unsigned short* __restrict__ w1T,
    const int* __restrict__ y,
    float* __restrict__ scal)
{
  __shared__ __align__(16) char lds[49152];
  unsigned short* As     = (unsigned short*)lds;            // 16 x 1KB
  unsigned short* Bs     = (unsigned short*)(lds + 16384);  // 32 x 1KB
  unsigned short* transH = (unsigned short*)lds;            // epilogue: 32 x 1KB (h half, frag-tiled)
  __shared__ __align__(16) unsigned short w1s[4096];        // 8 x 1KB w1 B-tiles
  __shared__ float redc[8], reda[8];

  int blk = blockIdx.x;
  int t = threadIdx.x;
  int wv = t >> 6, lane = t & 63, ln = lane & 15, quad = lane >> 4;
  int wr = wv >> 2, wc = wv & 3;
  int rep = (blk ^ (blk >> 4)) & (NREP-1);

  *(short8*)&w1s[t*8] = *(const short8*)&w1T[t*8];

  const f32x4 zv = {0.f,0.f,0.f,0.f};
  f32x4 acc[4][4];
  #pragma unroll
  for (int rt=0;rt<4;++rt)
    #pragma unroll
    for (int ct=0;ct<4;++ct) acc[rt][ct] = zv;

  const char* ab = (const char*)x4T;
  const char* bb = (const char*)wT;

  for (int kt = 0; kt < 8; ++kt){
    {
      size_t Ig = (size_t)(blk*8 + wv);
      GLL(ab + ((Ig*16 + kt*2 + 0) << 10) + lane*16, (char*)As + ((wv*2+0) << 10));
      GLL(ab + ((Ig*16 + kt*2 + 1) << 10) + lane*16, (char*)As + ((wv*2+1) << 10));
    }
    #pragma unroll
    for (int i = 0; i < 2; ++i)
      #pragma unroll
      for (int c = 0; c < 2; ++c){
        size_t Jg = (size_t)(wv*2 + i);
        GLL(bb + ((Jg*16 + kt*2 + c) << 10) + lane*16,
            (char*)Bs + (((wv*2+i)*2 + c) << 10));
      }
    __syncthreads();
    #pragma unroll
    for (int c = 0; c < 2; ++c){
      short8 a[4];
      #pragma unroll
      for (int rt=0;rt<4;++rt)
        a[rt] = *(const short8*)&As[(((wr*4+rt)*2 + c) << 9) + lane*8];
      #pragma unroll
      for (int ct=0;ct<4;++ct){
        short8 b = *(const short8*)&Bs[(((wc*4+ct)*2 + c) << 9) + lane*8];
        #pragma unroll
        for (int rt=0;rt<4;++rt)
          acc[rt][ct] = __builtin_amdgcn_mfma_f32_16x16x32_bf16(a[rt], b, acc[rt][ct], 0,0,0);
      }
    }
    __syncthreads();
  }

  // epilogue: per 128-col half, write relu(h) fragment-tiled -> logits MFMA
  f32x4 alog = zv;
  #pragma unroll
  for (int hf = 0; hf < 2; ++hf){
    __syncthreads();
    if ((wc >> 1) == hf){
      #pragma unroll
      for (int rt=0;rt<4;++rt)
        #pragma unroll
        for (int ct=0;ct<4;++ct)
          #pragma unroll
          for (int r=0;r<4;++r){
            int row_l = wr*64 + rt*16 + quad*4 + r;
            int ch = (wc & 1)*64 + ct*16 + ln;
            int tile = ((row_l >> 4) << 2) | (ch >> 5);
            int slot = (row_l & 15) | (((ch >> 3) & 3) << 4);
            transH[(tile << 9) + slot*8 + (ch & 7)] = f2b(fmaxf(acc[rt][ct][r], 0.f));
          }
    }
    __syncthreads();
    #pragma unroll
    for (int Cl = 0; Cl < 4; ++Cl){
      short8 a = *(const short8*)&transH[((wv*4 + Cl) << 9) + lane*8];
      short8 b = *(const short8*)&w1s[(hf*4 + Cl)*512 + lane*8];
      alog = __builtin_amdgcn_mfma_f32_16x16x32_bf16(a, b, alog, 0,0,0);
    }
  }

  // CE/argmax: logits for row (wv*16 + quad*4 + r), class = ln
  float ce_l = 0.f, acc_l = 0.f;
  #pragma unroll
  for (int r = 0; r < 4; ++r){
    int grow = blk*128 + wv*16 + quad*4 + r;
    int yv = y[grow];
    float lg = (ln < NC) ? alog[r] : -1e30f;
    float m = lg; int mi = ln;
    #pragma unroll
    for (int mk = 1; mk < 16; mk <<= 1){
      float om = __shfl_xor(m, mk); int oi = __shfl_xor(mi, mk);
      if (om > m || (om == m && oi < mi)){ m = om; mi = oi; }
    }
    float e  = (ln < NC) ? __expf(lg - m) : 0.f;
    float sy = (ln == yv) ? lg : 0.f;
    #pragma unroll
    for (int mk = 1; mk < 16; mk <<= 1){ e += __shfl_xor(e, mk); sy += __shfl_xor(sy, mk); }
    float lse = m + __logf(e);
    if (ln == 0){ ce_l += (lse - sy); acc_l += (mi == yv) ? 1.f : 0.f; }
  }
  ce_l  += __shfl_down(ce_l, 16);  acc_l += __shfl_down(acc_l, 16);
  ce_l  += __shfl_down(ce_l, 32);  acc_l += __shfl_down(acc_l, 32);
  if (lane == 0){ redc[wv] = ce_l; reda[wv] = acc_l; }
  __syncthreads();
  if (t == 0){
    float c = 0.f, a = 0.f;
    #pragma unroll
    for (int i=0;i<8;++i){ c += redc[i]; a += reda[i]; }
    atomicAdd(&scal[SCAL_CE  + rep], c);
    atomicAdd(&scal[SCAL_ACC + rep], a);
  }
}

// K3: reduce gsum/gcnt -> var term; finalize loss/acc. One block.
__global__ __launch_bounds__(1024) void k_final(const float* __restrict__ accb,
                                                float* __restrict__ out){
  const float* gsum = accb + GSUM_OFF;
  const float* gcnt = accb + CNT_OFF;
  int t = threadIdx.x;
  float contrib = 0.f;
  for (int idx = t; idx < 5120; idx += 1024){
    float S = 0.f;
    #pragma unroll
    for (int r = 0; r < NREP; ++r) S += gsum[(size_t)r*5120 + idx];
    int c = idx >> 9;
    float cnt = 0.f;
    #pragma unroll
    for (int r = 0; r < NREP; ++r) cnt += gcnt[r*16 + c];
    contrib += S*S / fmaxf(cnt, 1.f);
  }
  for (int off = 32; off; off >>= 1) contrib += __shfl_down(contrib, off);
  __shared__ float red[16];
  if ((t & 63) == 0) red[t >> 6] = contrib;
  __syncthreads();
  if (t == 0){
    float var2 = 0.f;
    #pragma unroll
    for (int i=0;i<16;++i) var2 += red[i];
    float sumsq=0.f, ce=0.f, acc=0.f, l1=0.f;
    for (int r=0;r<NREP;++r){
      sumsq += accb[SCAL_SUMSQ+r];
      ce    += accb[SCAL_CE+r];
      acc   += accb[SCAL_ACC+r];
      l1    += accb[SCAL_L1+r];
    }
    float var_loss = sumsq - var2;
    out[0] = ce/(float)BATCH + 1e-4f*l1 + 1e-3f*var_loss;
    out[1] = acc/(float)BATCH;
  }
}

extern "C" void kernel_launch(void* const* d_in, const int* in_sizes, int n_in,
                              void* d_out, int out_size, void* d_ws, size_t ws_size,
                              hipStream_t stream){
  (void)in_sizes; (void)n_in; (void)out_size; (void)ws_size;
  const float* x   = (const float*)d_in[0];
  const int*   y   = (const int*)d_in[1];
  const float* fc0 = (const float*)d_in[2];
  const float* fc1 = (const float*)d_in[3];
  const float* w   = (const float*)d_in[4];
  const float* w1  = (const float*)d_in[5];
  char* ws = (char*)d_ws;
  unsigned short* fc0T = (unsigned short*)(ws + OFF_FC0T);
  unsigned short* fc1T = (unsigned short*)(ws + OFF_FC1T);
  unsigned short* wT   = (unsigned short*)(ws + OFF_WT);
  unsigned short* xT   = (unsigned short*)(ws + OFF_XT);
  unsigned short* x4T  = (unsigned short*)(ws + OFF_X4T);
  unsigned short* w1T  = (unsigned short*)(ws + OFF_W1T);
  float* accb = (float*)(ws + OFF_ACC);
  float* scal = accb;
  float* gcnt = accb + CNT_OFF;
  float* gsum = accb + GSUM_OFF;

  static bool once = [](){
    hipFuncSetAttribute((const void*)k_gemm12,
                        hipFuncAttributeMaxDynamicSharedMemorySize, 131072);
    return true;
  }();
  (void)once;

  k_setup<<<1441, 256, 0, stream>>>(x, fc0, fc1, w, w1, xT, fc0T, fc1T, wT, w1T, accb);
  k_gemm12<<<1024, 512, 131072, stream>>>(xT, fc0T, fc1T, x4T, scal);
  k_cnt<<<32, 256, 0, stream>>>(y, gcnt);
  k_csum<<<256, 256, 0, stream>>>(x4T, y, gsum);
  k_gemm3_head<<<512, 512, 0, stream>>>(x4T, wT, w1T, y, scal);
  k_final<<<1, 1024, 0, stream>>>(accb, (float*)d_out);
}

// Round 2
// 399.347 us; speedup vs baseline: 1.0268x; 1.0128x over previous
//
#include <hip/hip_runtime.h>
#include <stdint.h>

#define BATCH 65536
#define FDIM 512
#define HDIM 256
#define NC 10
#define NREP 16

typedef short short8 __attribute__((ext_vector_type(8)));
typedef float f32x4 __attribute__((ext_vector_type(4)));

// ---- workspace layout (bytes) ----
// Fragment-tiled layout: tile (I=row/16, C=k/32) is 1KB at (I*nC + C)*1024;
// slot l = (row&15) | (((k>>3)&3)<<4) holds 8 bf16 (k = (l>>4)*8 .. +7).
#define OFF_FC0T   ((size_t)0)                          // 32 J x 16 C tiles
#define OFF_FC1T   (OFF_FC0T + (size_t)512*512*2)
#define OFF_WT     (OFF_FC1T + (size_t)512*512*2)       // 16 J x 16 C tiles
#define OFF_XT     (OFF_WT   + (size_t)256*512*2)       // 4096 I x 16 C (64MB)
#define OFF_X4T    (OFF_XT   + (size_t)BATCH*512*2)     // 4096 I x 16 C (64MB)
#define OFF_ACC    (OFF_X4T  + (size_t)BATCH*512*2)
#define SCAL_SUMSQ 0
#define SCAL_CE    16
#define SCAL_ACC   32
#define SCAL_L1    48
#define SCAL_N     128
#define CNT_OFF    SCAL_N                 // NREP*16 floats
#define GSUM_OFF   (SCAL_N + NREP*16)     // NREP*5120 floats
#define ACC_FLOATS (GSUM_OFF + NREP*5120) // 82304 floats
#define OFF_W1T    (OFF_ACC + (size_t)ACC_FLOATS*4)     // 8 C-tiles x 1KB (w1 bf16, padded to 16 classes)

#define GLL(g,l) __builtin_amdgcn_global_load_lds((const __attribute__((address_space(1))) void*)(g), (__attribute__((address_space(3))) void*)(l), 16, 0, 0)

__device__ __forceinline__ unsigned short f2b(float f){
  unsigned u = __float_as_uint(f);
  u += 0x7FFFu + ((u >> 16) & 1u);
  return (unsigned short)(u >> 16);
}
__device__ __forceinline__ float b2f(unsigned short h){
  return __uint_as_float(((unsigned)h) << 16);
}
__device__ __forceinline__ unsigned pk2b(float f0, float f1){
  unsigned u0 = __float_as_uint(f0) + 0x8000u;
  unsigned u1 = __float_as_uint(f1) + 0x8000u;
  return __builtin_amdgcn_perm(u1, u0, 0x07060302u);
}

// ---- K0: setup — xcast (0..1023), weight prep (1024..1359), zero (1360..1440),
//      class counts (1441..1456; private slots, no zero dependency)
__global__ __launch_bounds__(256) void k_setup(
    const float* __restrict__ x,   const float* __restrict__ fc0,
    const float* __restrict__ fc1, const float* __restrict__ w,
    const float* __restrict__ w1,  const int* __restrict__ y,
    unsigned short* __restrict__ xT,   unsigned short* __restrict__ fc0T,
    unsigned short* __restrict__ fc1T, unsigned short* __restrict__ wT,
    unsigned short* __restrict__ w1T,  float* __restrict__ accb)
{
  int blk = blockIdx.x, t = threadIdx.x;
  if (blk < 1024){
    int I = blk*4 + (t >> 6);
    int l = t & 63;
    int row = I*16 + (l & 15), q = l >> 4;
    const float* src = x + (size_t)row*FDIM + q*8;
    #pragma unroll
    for (int C = 0; C < 16; ++C){
      float4 v0 = *(const float4*)(src + C*32);
      float4 v1 = *(const float4*)(src + C*32 + 4);
      unsigned o[4];
      o[0] = pk2b(v0.x, v0.y); o[1] = pk2b(v0.z, v0.w);
      o[2] = pk2b(v1.x, v1.y); o[3] = pk2b(v1.z, v1.w);
      *(short8*)&xT[(((size_t)I*16 + C) << 9) + l*8] = *(short8*)o;
    }
    return;
  }
  if (blk < 1360){
    int i = (blk - 1024)*256 + t;
    float l1v = 0.f;
    if (i < 32768){                       // fc0 [k][512] -> tiled
      int n4 = i&15, m = (i>>4)&3, C = (i>>6)&15, J = i>>10;
      int n = J*16+n4, k8 = C*4+m;
      unsigned short o[8];
      #pragma unroll
      for (int j=0;j<8;++j){ float v = fc0[(size_t)(k8*8+j)*512 + n]; o[j]=f2b(v); l1v += fabsf(v); }
      *(short8*)&fc0T[(size_t)(J*16+C)*512 + (i&63)*8] = *(short8*)o;
    } else if (i < 65536){                // fc1
      int j0 = i - 32768;
      int n4 = j0&15, m = (j0>>4)&3, C = (j0>>6)&15, J = j0>>10;
      int n = J*16+n4, k8 = C*4+m;
      unsigned short o[8];
      #pragma unroll
      for (int j=0;j<8;++j){ float v = fc1[(size_t)(k8*8+j)*512 + n]; o[j]=f2b(v); l1v += fabsf(v); }
      *(short8*)&fc1T[(size_t)(J*16+C)*512 + (j0&63)*8] = *(short8*)o;
    } else if (i < 81920){                // w [k][256]
      int j0 = i - 65536;
      int n4 = j0&15, m = (j0>>4)&3, C = (j0>>6)&15, J = j0>>10;
      int n = J*16+n4, k8 = C*4+m;
      unsigned short o[8];
      #pragma unroll
      for (int j=0;j<8;++j){ float v = w[(size_t)(k8*8+j)*256 + n]; o[j]=f2b(v); l1v += fabsf(v); }
      *(short8*)&wT[(size_t)(J*16+C)*512 + (j0&63)*8] = *(short8*)o;
    } else if (i < 86016){                // w1 -> B-fragment tiles (16 classes padded), + L1
      int j0 = i - 81920;                 // 0..4095, one bf16 each
      int C = j0 >> 9, l = (j0 >> 3) & 63, e = j0 & 7;
      int n = l & 15, k = C*32 + (l>>4)*8 + e;
      float v = (n < NC) ? w1[k*NC + n] : 0.f;
      w1T[C*512 + l*8 + e] = f2b(v);
      if (n < NC) l1v = fabsf(v);
    }
    for (int off = 32; off; off >>= 1) l1v += __shfl_down(l1v, off);
    if ((t & 63) == 0 && l1v != 0.f)
      atomicAdd(&accb[SCAL_L1 + (blk & (NREP-1))], l1v);
    return;
  }
  if (blk < 1441){
    int base = (blk - 1360)*1024;
    #pragma unroll
    for (int j=0;j<4;++j){
      int idx = base + j*256 + t;
      // exclude CNT region [CNT_OFF, CNT_OFF+256): fully written by cnt blocks
      if (idx < ACC_FLOATS && (idx < CNT_OFF || idx >= CNT_OFF + NREP*16))
        accb[idx] = 0.f;
    }
    return;
  }
  {
    // class counts: 16 blocks, 4096 labels each, private gcnt slot (no atomics on global)
    __shared__ float cntS[16];
    int b = blk - 1441;
    if (t < 16) cntS[t] = 0.f;
    __syncthreads();
    int base = b*4096;
    for (int i = t; i < 4096; i += 256) atomicAdd(&cntS[y[base+i]], 1.f);
    __syncthreads();
    if (t < 16) accb[CNT_OFF + b*16 + t] = cntS[t];
  }
}

// ---------------------------------------------------------------------------
// Shared 2-phase read-once K-loop machinery (k_gemm12 / k_gemm3_head).
// Block = 256 rows x (128 cols x 2 matrices); 8 waves (2r x 4c); BK=64;
// double-buffered 128KB LDS (A 32KB + B0 16KB + B1 16KB per buffer).
// Per K-tile: P0 reads {A-h0(8), B0(4), B1(4)}, stages kt+1 {A-h1,B1} -> buf^1;
//             P1 reads {A-h1(8)},             stages kt+2 {A-h0,B0} -> cur.
// B0/B1 held in registers across both phases (24 ds_reads / 64 MFMA / K-tile).
// vmcnt(4) once per K-tile retires exactly kt+1's four half-tiles (T4).
// Anti-deps: P0's targets last read at kt-1 (past kt-start barrier); P1's
// targets (cur A-h0/B0) last read in this kt's P0, separated by P0 barriers.
// ---------------------------------------------------------------------------

#define BARRIER() __builtin_amdgcn_s_barrier()
#define LGKM0() do{ asm volatile("s_waitcnt lgkmcnt(0)" ::: "memory"); \
                    __builtin_amdgcn_sched_barrier(0); }while(0)

#define READA(A, AB, H) do{                                                   \
  _Pragma("unroll") for (int c_=0;c_<2;++c_)                                  \
  _Pragma("unroll") for (int m_=0;m_<4;++m_)                                  \
    A[c_][m_] = *(const short8*)((AB) + (((wr*8 + (H)*4 + m_)*2 + c_)<<10) + lane*16); \
}while(0)

#define READB(B, BB, MAT) do{                                                 \
  _Pragma("unroll") for (int c_=0;c_<2;++c_)                                  \
  _Pragma("unroll") for (int n_=0;n_<2;++n_)                                  \
    B[c_][n_] = *(const short8*)((BB) + (MAT)*16384 + (((wc*2+n_)*2 + c_)<<10) + lane*16); \
}while(0)

// 32 MFMA: a x b0 -> acc1[MB..MB+3], a x b1 -> acc2[MB..MB+3]
#define MMALL(MB) do{                                                         \
  __builtin_amdgcn_s_setprio(1);                                              \
  _Pragma("unroll") for (int c_=0;c_<2;++c_)                                  \
  _Pragma("unroll") for (int n_=0;n_<2;++n_)                                  \
  _Pragma("unroll") for (int m_=0;m_<4;++m_)                                  \
    acc1[(MB)+m_][n_] = __builtin_amdgcn_mfma_f32_16x16x32_bf16(a[c_][m_], b0[c_][n_], acc1[(MB)+m_][n_], 0,0,0); \
  _Pragma("unroll") for (int c_=0;c_<2;++c_)                                  \
  _Pragma("unroll") for (int n_=0;n_<2;++n_)                                  \
  _Pragma("unroll") for (int m_=0;m_<4;++m_)                                  \
    acc2[(MB)+m_][n_] = __builtin_amdgcn_mfma_f32_16x16x32_bf16(a[c_][m_], b1[c_][n_], acc2[(MB)+m_][n_], 0,0,0); \
  __builtin_amdgcn_s_setprio(0);                                              \
}while(0)

// stage one 16KB A-half (8 I-tiles x 2 C): wave wv does tiles {wv, 8+wv}
#define STAGEA(KT2, H) do{                                                    \
  char* d_ = ldsd + (((KT2)&1) ? 65536 : 0);                                  \
  _Pragma("unroll") for (int r_=0;r_<2;++r_){                                 \
    int idx_ = r_*8 + wv, q_ = idx_>>1, C_ = idx_&1;                          \
    int Il_ = (q_&3) + ((q_>>2)<<3) + (H)*4;                                  \
    GLL(xb + (((size_t)((rowblk*16 + Il_)*16 + (KT2)*2 + C_)) << 10) + lane*16, \
        d_ + ((Il_*2 + C_) << 10) + lane*16);                                 \
  } }while(0)

// stage one 16KB B-half (one matrix's 8 J-tiles x 2 C)
#define STAGEB(KT2, MAT) do{                                                  \
  char* d_ = ldsd + (((KT2)&1) ? 65536 : 0) + 32768 + (MAT)*16384;            \
  const char* s_ = (MAT) ? b1b : b0b;                                         \
  _Pragma("unroll") for (int r_=0;r_<2;++r_){                                 \
    int idx_ = r_*8 + wv, J_ = idx_>>1, C_ = idx_&1;                          \
    GLL(s_ + (((size_t)((colblk*8 + J_)*16 + (KT2)*2 + C_)) << 10) + lane*16, \
        d_ + ((J_*2 + C_) << 10) + lane*16);                                  \
  } }while(0)

#define KLOOP_PROLOGUE() do{                                                  \
  STAGEA(0,0); STAGEA(0,1); STAGEB(0,0); STAGEB(0,1);                         \
  STAGEA(1,0); STAGEB(1,0);                                                   \
  asm volatile("s_waitcnt vmcnt(4)" ::: "memory");                            \
  __builtin_amdgcn_sched_barrier(0);                                          \
  BARRIER();                                                                  \
}while(0)

#define KLOOP_BODY(kt) do{                                                    \
  char* Ab = ldsd + (((kt)&1) ? 65536 : 0);                                   \
  char* Bb = Ab + 32768;                                                      \
  /* P0 */                                                                    \
  READA(a, Ab, 0);                                                            \
  READB(b0, Bb, 0);                                                           \
  READB(b1, Bb, 1);                                                           \
  if ((kt) < 7){ STAGEA((kt)+1, 1); STAGEB((kt)+1, 1); }                      \
  BARRIER(); LGKM0();                                                         \
  MMALL(0);                                                                   \
  BARRIER();                                                                  \
  /* P1 */                                                                    \
  READA(a, Ab, 1);                                                            \
  if ((kt) < 6){ STAGEA((kt)+2, 0); STAGEB((kt)+2, 0); }                      \
  BARRIER(); LGKM0();                                                         \
  MMALL(4);                                                                   \
  if ((kt) < 6)       { asm volatile("s_waitcnt vmcnt(4)" ::: "memory"); }    \
  else if ((kt) == 6) { asm volatile("s_waitcnt vmcnt(0)" ::: "memory"); }    \
  __builtin_amdgcn_sched_barrier(0);                                          \
  BARRIER();                                                                  \
}while(0)

// K1: dual GEMM x@fc0, x@fc1 + gated residual epilogue.
__global__ __launch_bounds__(512, 2) void k_gemm12(
    const unsigned short* __restrict__ xT,
    const unsigned short* __restrict__ fc0T,
    const unsigned short* __restrict__ fc1T,
    unsigned short* __restrict__ x4T,
    float* __restrict__ scal)
{
  extern __shared__ __align__(16) char ldsd[];   // 131072 dynamic

  int blk = blockIdx.x;
  int wg = (blk & 7)*128 + (blk >> 3);           // bijective XCD chunking (1024%8==0)
  int rowblk = wg >> 2;                          // 0..255 (256 rows each)
  int colblk = wg & 3;                           // 0..3   (128 cols each)

  int t = threadIdx.x;
  int wv = t >> 6, lane = t & 63, ln = lane & 15, quad = lane >> 4;
  int wr = wv >> 2, wc = wv & 3;                 // 2 x 4 wave grid

  const char* xb  = (const char*)xT;
  const char* b0b = (const char*)fc0T;
  const char* b1b = (const char*)fc1T;

  const f32x4 zv = {0.f,0.f,0.f,0.f};
  f32x4 acc1[8][2], acc2[8][2];
  #pragma unroll
  for (int m=0;m<8;++m){ acc1[m][0]=zv; acc1[m][1]=zv; acc2[m][0]=zv; acc2[m][1]=zv; }

  short8 a[2][4], b0[2][2], b1[2][2];

  KLOOP_PROLOGUE();
  for (int kt = 0; kt < 8; ++kt) KLOOP_BODY(kt);

  // ---- epilogue: residual x into buf0 region, x4 bf16 into buf1 region
  {
    int Cres = colblk*4 + wc;
    #pragma unroll
    for (int i = 0; i < 8; ++i){
      GLL(xb + (((size_t)((rowblk*16 + wr*8 + i)*16 + Cres)) << 10) + lane*16,
          ldsd + ((wv*8 + i) << 10) + lane*16);
    }
    asm volatile("s_waitcnt vmcnt(0)" ::: "memory");
  }
  __syncthreads();

  unsigned short* resU = (unsigned short*)ldsd;
  unsigned short* x4U  = (unsigned short*)(ldsd + 65536);
  float sumsq = 0.f;
  #pragma unroll
  for (int m = 0; m < 8; ++m){
    #pragma unroll
    for (int n = 0; n < 2; ++n){
      #pragma unroll
      for (int r = 0; r < 4; ++r){
        int slot = (quad*4 + r) | ((n*2 + (ln>>3)) << 4);
        int idx = ((wv*8 + m) << 9) + slot*8 + (ln & 7);
        float xv  = b2f(resU[idx]);
        float x1v = acc1[m][n][r];
        float x2v = fmaxf(acc2[m][n][r], 0.f);
        float gate = 1.f + 1.f/(1.f + __expf(-x1v));
        float x4v = fmaf(gate, x2v, xv);
        unsigned short ub = f2b(x4v);
        float fq = b2f(ub);
        sumsq = fmaf(fq, fq, sumsq);
        x4U[idx] = ub;
      }
    }
  }
  for (int off = 32; off; off >>= 1) sumsq += __shfl_down(sumsq, off);
  __syncthreads();                         // all res reads + x4 writes done
  float* red = (float*)ldsd;               // overwrite dead res region
  if (lane == 0) red[wv] = sumsq;
  __syncthreads();
  if (t == 0){
    float s = 0.f;
    #pragma unroll
    for (int i=0;i<8;++i) s += red[i];
    atomicAdd(&scal[SCAL_SUMSQ + (blk & (NREP-1))], s);
  }
  // copy x4 LDS -> global (16B stores)
  #pragma unroll
  for (int r = 0; r < 2; ++r){
    int o = r*512 + t;
    int tile = o >> 6, off16 = o & 63;
    int wvp = tile >> 3, i = tile & 7;
    size_t Ig = (size_t)rowblk*16 + (wvp>>2)*8 + i;
    int Cg = colblk*4 + (wvp & 3);
    *(short8*)&x4T[((Ig*16 + Cg) << 9) + off16*8] =
      *(const short8*)&x4U[(tile << 9) + off16*8];
  }
}

// class sums from tiled x4: one wave per (C-phase, 64 I-tiles)
__global__ __launch_bounds__(256) void k_csum(const unsigned short* __restrict__ x4T,
                                              const int* __restrict__ y,
                                              float* __restrict__ gsum){
  int w = blockIdx.x*4 + (threadIdx.x >> 6);   // 1024 waves
  int l = threadIdx.x & 63;
  int C = w & 15, Ig = w >> 4;                 // Ig 0..63
  int rl = l & 15, q = l >> 4;
  float a[NC][8];
  #pragma unroll
  for (int c=0;c<NC;++c)
    #pragma unroll
    for (int e=0;e<8;++e) a[c][e]=0.f;
  for (int ii = 0; ii < 64; ++ii){
    int I = Ig*64 + ii;
    int yv = y[I*16 + rl];
    short8 v = *(const short8*)&x4T[(((size_t)I*16 + C) << 9) + l*8];
    float f[8];
    #pragma unroll
    for (int e=0;e<8;++e) f[e] = b2f((unsigned short)v[e]);
    #pragma unroll
    for (int c=0;c<NC;++c){
      bool m = (yv == c);
      #pragma unroll
      for (int e=0;e<8;++e) a[c][e] += m ? f[e] : 0.f;
    }
  }
  #pragma unroll
  for (int off = 1; off < 16; off <<= 1)
    #pragma unroll
    for (int c=0;c<NC;++c)
      #pragma unroll
      for (int e=0;e<8;++e) a[c][e] += __shfl_xor(a[c][e], off);
  if (rl == 0){
    int rep = Ig & (NREP-1);
    int kb = C*32 + q*8;
    #pragma unroll
    for (int c=0;c<NC;++c)
      #pragma unroll
      for (int e=0;e<8;++e)
        atomicAdd(&gsum[(size_t)rep*5120 + c*512 + kb + e], a[c][e]);
  }
}

// K2: h = relu(x4 @ w); logits = h @ w1; CE/argmax/acc.
// Same 2-phase template: block = 256 rows x 256 w-cols (B0 = w[:,0:128],
// B1 = w[:,128:256]); grid 256 blocks, 1/CU.
__global__ __launch_bounds__(512, 2) void k_gemm3_head(
    const unsigned short* __restrict__ x4T,
    const unsigned short* __restrict__ wT,
    const unsigned short* __restrict__ w1T,
    const int* __restrict__ y,
    float* __restrict__ scal)
{
  extern __shared__ __align__(16) char ldsd[];   // 131072 dynamic
  __shared__ float redc[8], reda[8];

  int blk = blockIdx.x;
  int rowblk = blk;                              // 256 rows each
  const int colblk = 0;

  int t = threadIdx.x;
  int wv = t >> 6, lane = t & 63, ln = lane & 15, quad = lane >> 4;
  int wr = wv >> 2, wc = wv & 3;
  int rep = (blk ^ (blk >> 4)) & (NREP-1);

  const char* xb  = (const char*)x4T;
  const char* b0b = (const char*)wT;                       // w cols 0..127 (J 0..7)
  const char* b1b = (const char*)wT + (size_t)128*1024;    // w cols 128..255 (J 8..15)

  const f32x4 zv = {0.f,0.f,0.f,0.f};
  f32x4 acc1[8][2], acc2[8][2];
  #pragma unroll
  for (int m=0;m<8;++m){ acc1[m][0]=zv; acc1[m][1]=zv; acc2[m][0]=zv; acc2[m][1]=zv; }

  short8 a[2][4], b0[2][2], b1[2][2];

  KLOOP_PROLOGUE();
  for (int kt = 0; kt < 8; ++kt) KLOOP_BODY(kt);

  // w1 B-fragments from global (8KB, L2-resident), hidden under transH writes
  short8 bw1[8];
  #pragma unroll
  for (int Ck = 0; Ck < 8; ++Ck)
    bw1[Ck] = *(const short8*)&w1T[Ck*512 + lane*8];

  // h = relu(acc) fragment-tiled into the (dead) full 128KB LDS:
  // tile (Ih*8 + Ck), Ih = row>>4 (16), Ck = hcol>>5 (8)
  unsigned short* transH = (unsigned short*)ldsd;
  #pragma unroll
  for (int m = 0; m < 8; ++m){
    #pragma unroll
    for (int n = 0; n < 2; ++n){
      #pragma unroll
      for (int r = 0; r < 4; ++r){
        int slot = (quad*4 + r) | ((n*2 + (ln>>3)) << 4);
        int e = ln & 7;
        int IhA = wr*8 + m;
        // mat 0: Ck = wc ; mat 1: Ck = 4 + wc
        transH[((IhA*8 + wc)     << 9) + slot*8 + e] = f2b(fmaxf(acc1[m][n][r], 0.f));
        transH[((IhA*8 + 4 + wc) << 9) + slot*8 + e] = f2b(fmaxf(acc2[m][n][r], 0.f));
      }
    }
  }
  __syncthreads();

  // logits: each wave handles row-tiles Ih = wv*2 + {0,1}
  f32x4 alog[2] = {zv, zv};
  #pragma unroll
  for (int ih = 0; ih < 2; ++ih){
    int Ih = wv*2 + ih;
    #pragma unroll
    for (int Ck = 0; Ck < 8; ++Ck){
      short8 af = *(const short8*)&transH[((Ih*8 + Ck) << 9) + lane*8];
      alog[ih] = __builtin_amdgcn_mfma_f32_16x16x32_bf16(af, bw1[Ck], alog[ih], 0,0,0);
    }
  }

  // CE/argmax: row = blk*256 + Ih*16 + quad*4 + r, class = ln
  float ce_l = 0.f, acc_l = 0.f;
  #pragma unroll
  for (int ih = 0; ih < 2; ++ih){
    #pragma unroll
    for (int r = 0; r < 4; ++r){
      int grow = blk*256 + (wv*2 + ih)*16 + quad*4 + r;
      int yv = y[grow];
      float lg = (ln < NC) ? alog[ih][r] : -1e30f;
      float m = lg; int mi = ln;
      #pragma unroll
      for (int mk = 1; mk < 16; mk <<= 1){
        float om = __shfl_xor(m, mk); int oi = __shfl_xor(mi, mk);
        if (om > m || (om == m && oi < mi)){ m = om; mi = oi; }
      }
      float e  = (ln < NC) ? __expf(lg - m) : 0.f;
      float sy = (ln == yv) ? lg : 0.f;
      #pragma unroll
      for (int mk = 1; mk < 16; mk <<= 1){ e += __shfl_xor(e, mk); sy += __shfl_xor(sy, mk); }
      float lse = m + __logf(e);
      if (ln == 0){ ce_l += (lse - sy); acc_l += (mi == yv) ? 1.f : 0.f; }
    }
  }
  ce_l  += __shfl_down(ce_l, 16);  acc_l += __shfl_down(acc_l, 16);
  ce_l  += __shfl_down(ce_l, 32);  acc_l += __shfl_down(acc_l, 32);
  if (lane == 0){ redc[wv] = ce_l; reda[wv] = acc_l; }
  __syncthreads();
  if (t == 0){
    float c = 0.f, aa = 0.f;
    #pragma unroll
    for (int i=0;i<8;++i){ c += redc[i]; aa += reda[i]; }
    atomicAdd(&scal[SCAL_CE  + rep], c);
    atomicAdd(&scal[SCAL_ACC + rep], aa);
  }
}

// K3: reduce gsum/gcnt -> var term; finalize loss/acc. One block.
__global__ __launch_bounds__(1024) void k_final(const float* __restrict__ accb,
                                                float* __restrict__ out){
  const float* gsum = accb + GSUM_OFF;
  const float* gcnt = accb + CNT_OFF;
  int t = threadIdx.x;
  float contrib = 0.f;
  for (int idx = t; idx < 5120; idx += 1024){
    float S = 0.f;
    #pragma unroll
    for (int r = 0; r < NREP; ++r) S += gsum[(size_t)r*5120 + idx];
    int c = idx >> 9;
    float cnt = 0.f;
    #pragma unroll
    for (int r = 0; r < NREP; ++r) cnt += gcnt[r*16 + c];
    contrib += S*S / fmaxf(cnt, 1.f);
  }
  for (int off = 32; off; off >>= 1) contrib += __shfl_down(contrib, off);
  __shared__ float red[16];
  if ((t & 63) == 0) red[t >> 6] = contrib;
  __syncthreads();
  if (t == 0){
    float var2 = 0.f;
    #pragma unroll
    for (int i=0;i<16;++i) var2 += red[i];
    float sumsq=0.f, ce=0.f, acc=0.f, l1=0.f;
    for (int r=0;r<NREP;++r){
      sumsq += accb[SCAL_SUMSQ+r];
      ce    += accb[SCAL_CE+r];
      acc   += accb[SCAL_ACC+r];
      l1    += accb[SCAL_L1+r];
    }
    float var_loss = sumsq - var2;
    out[0] = ce/(float)BATCH + 1e-4f*l1 + 1e-3f*var_loss;
    out[1] = acc/(float)BATCH;
  }
}

extern "C" void kernel_launch(void* const* d_in, const int* in_sizes, int n_in,
                              void* d_out, int out_size, void* d_ws, size_t ws_size,
                              hipStream_t stream){
  (void)in_sizes; (void)n_in; (void)out_size; (void)ws_size;
  const float* x   = (const float*)d_in[0];
  const int*   y   = (const int*)d_in[1];
  const float* fc0 = (const float*)d_in[2];
  const float* fc1 = (const float*)d_in[3];
  const float* w   = (const float*)d_in[4];
  const float* w1  = (const float*)d_in[5];
  char* ws = (char*)d_ws;
  unsigned short* fc0T = (unsigned short*)(ws + OFF_FC0T);
  unsigned short* fc1T = (unsigned short*)(ws + OFF_FC1T);
  unsigned short* wT   = (unsigned short*)(ws + OFF_WT);
  unsigned short* xT   = (unsigned short*)(ws + OFF_XT);
  unsigned short* x4T  = (unsigned short*)(ws + OFF_X4T);
  unsigned short* w1T  = (unsigned short*)(ws + OFF_W1T);
  float* accb = (float*)(ws + OFF_ACC);
  float* scal = accb;
  float* gsum = accb + GSUM_OFF;

  static bool once = [](){
    hipFuncSetAttribute((const void*)k_gemm12,
                        hipFuncAttributeMaxDynamicSharedMemorySize, 131072);
    hipFuncSetAttribute((const void*)k_gemm3_head,
                        hipFuncAttributeMaxDynamicSharedMemorySize, 131072);
    return true;
  }();
  (void)once;

  k_setup<<<1457, 256, 0, stream>>>(x, fc0, fc1, w, w1, y, xT, fc0T, fc1T, wT, w1T, accb);
  k_gemm12<<<1024, 512, 131072, stream>>>(xT, fc0T, fc1T, x4T, scal);
  k_csum<<<256, 256, 0, stream>>>(x4T, y, gsum);
  k_gemm3_head<<<256, 512, 131072, stream>>>(x4T, wT, w1T, y, scal);
  k_final<<<1, 1024, 0, stream>>>(accb, (float*)d_out);
}